// Round 6
// baseline (554.938 us; speedup 1.0000x reference)
//
#include <hip/hip_runtime.h>
#include <math.h>
#include <stdint.h>

typedef unsigned short u16;
typedef unsigned int u32;

typedef __attribute__((ext_vector_type(8))) short bf16x8;
typedef __attribute__((ext_vector_type(4))) float f32x4;

#define ASYNC_COPY16(g, l)                                                         \
  __builtin_amdgcn_global_load_lds((__attribute__((address_space(1))) const void*)(g), \
                                   (__attribute__((address_space(3))) void*)(l), 16, 0, 0)

__device__ __forceinline__ float bf2f(u16 u) {
  union { u32 i; float f; } v; v.i = ((u32)u) << 16; return v.f;
}
__device__ __forceinline__ u16 f2bf(float f) {
  union { float f; u32 i; } v; v.f = f;
  u32 r = v.i + 0x7fffu + ((v.i >> 16) & 1u);
  return (u16)(r >> 16);
}
// fast GELU (tanh form via sigmoid): x*sigmoid(1.5957691*(x+0.044715*x^3))
__device__ __forceinline__ float gelu_fast(float x) {
  float t = x * x;
  float z = 1.5957691f * x * (1.0f + 0.044715f * t);
  return x / (1.0f + __expf(-z));
}

// ---------------------------------------------------------------------------
// K1-fused: blocks [0,4096): LayerNorm(x) + router logits + top-2 + atomic
// per-expert counts. blocks [4096, 4096+4608): grid-stride f32->bf16 weight
// conversion (18432 chunks of 2048 elems). The two jobs have independent
// inputs; fusing overlaps their memory streams (previously serialized on
// the stream: ~45us cvt THEN ~25us router).
// ---------------------------------------------------------------------------
__global__ __launch_bounds__(256) void pre_fused_k(
    const float* __restrict__ x, const float* __restrict__ g, const float* __restrict__ b,
    const float* __restrict__ rw, const float* __restrict__ rb,
    u16* __restrict__ xn, int* __restrict__ tk_idx, float* __restrict__ tk_w,
    int* __restrict__ cnt,
    const float* __restrict__ s0, const float* __restrict__ s1,
    const float* __restrict__ s2, const float* __restrict__ s3,
    u16* __restrict__ wdst)
{
  const int bid = blockIdx.x, tid = threadIdx.x;
  if (bid >= 4096) {
    // ---- weight conversion part (grid-stride over 18432 chunks) ----
    for (int c = bid - 4096; c < 18432; c += 4608) {
      const int64_t i0 = (int64_t)c * 2048 + (int64_t)tid * 8;
      const float* src; int64_t rel;
      if (i0 < 2097152)       { src = s0; rel = i0; }
      else if (i0 < 4194304)  { src = s1; rel = i0 - 2097152; }
      else if (i0 < 20971520) { src = s2; rel = i0 - 4194304; }
      else                    { src = s3; rel = i0 - 20971520; }
      const float4 a = *(const float4*)(src + rel);
      const float4 bb = *(const float4*)(src + rel + 4);
      union { u16 h[8]; uint4 v; } o;
      o.h[0] = f2bf(a.x);  o.h[1] = f2bf(a.y);  o.h[2] = f2bf(a.z);  o.h[3] = f2bf(a.w);
      o.h[4] = f2bf(bb.x); o.h[5] = f2bf(bb.y); o.h[6] = f2bf(bb.z); o.h[7] = f2bf(bb.w);
      *(uint4*)(wdst + i0) = o.v;
    }
    return;
  }
  // ---- router part: one block per token ----
  const int t = bid;
  __shared__ float xs[1024];
  __shared__ float red[8];
  __shared__ float logits[8];
  const int wave = tid >> 6, lane = tid & 63;

  const float4 xv = *(const float4*)(x + (size_t)t * 1024 + 4 * tid);
  float v0 = xv.x, v1 = xv.y, v2 = xv.z, v3 = xv.w;
  float s = v0 + v1 + v2 + v3;
  float q = v0 * v0 + v1 * v1 + v2 * v2 + v3 * v3;
#pragma unroll
  for (int o = 32; o > 0; o >>= 1) { s += __shfl_down(s, o, 64); q += __shfl_down(q, o, 64); }
  if (lane == 0) { red[wave] = s; red[4 + wave] = q; }
  __syncthreads();
  if (tid == 0) {
    float S = red[0] + red[1] + red[2] + red[3];
    float Q = red[4] + red[5] + red[6] + red[7];
    float mean = S * (1.0f / 1024.0f);
    float var = Q * (1.0f / 1024.0f) - mean * mean;
    red[0] = mean; red[1] = rsqrtf(var + 1e-5f);
  }
  __syncthreads();
  const float mean = red[0], rstd = red[1];
  float vv[4] = {v0, v1, v2, v3};
  union { u16 h[4]; uint2 v; } pk;
#pragma unroll
  for (int j = 0; j < 4; ++j) {
    int d = 4 * tid + j;
    float y = (vv[j] - mean) * rstd * g[d] + b[d];
    xs[d] = y;
    pk.h[j] = f2bf(y);
  }
  *(uint2*)(xn + (size_t)t * 1024 + 4 * tid) = pk.v;
  __syncthreads();
#pragma unroll
  for (int pe = 0; pe < 2; ++pe) {
    int e = wave + 4 * pe;
    const float* wrow = rw + (size_t)e * 1024;
    float acc = 0.f;
#pragma unroll
    for (int j = 0; j < 16; ++j) {
      int d = lane + 64 * j;
      acc += xs[d] * wrow[d];
    }
#pragma unroll
    for (int o = 32; o > 0; o >>= 1) acc += __shfl_down(acc, o, 64);
    if (lane == 0) logits[e] = acc + rb[e];
  }
  __syncthreads();
  if (tid == 0) {
    int i0 = 0; float l0 = logits[0];
#pragma unroll
    for (int e = 1; e < 8; ++e) if (logits[e] > l0) { l0 = logits[e]; i0 = e; }
    int i1 = -1; float l1 = -3.4e38f;
#pragma unroll
    for (int e = 0; e < 8; ++e) { if (e == i0) continue; if (logits[e] > l1) { l1 = logits[e]; i1 = e; } }
    float w0 = 1.0f / (1.0f + expf(l1 - l0));
    float w1 = 1.0f - w0;
    tk_idx[2 * t] = i0; tk_idx[2 * t + 1] = i1;
    tk_w[2 * t] = w0; tk_w[2 * t + 1] = w1;
    atomicAdd(&cnt[i0], 1);
    atomicAdd(&cnt[i1], 1);
  }
}

// ---------------------------------------------------------------------------
// K2: parallel slot scatter. 32 blocks x 256 threads = 8192 entries. Slot
// order within an expert segment is arbitrary (permuting slots changes no
// sums: each slot is processed independently and read back via slot_of),
// so per-expert atomic cursors are exact. Replaces the single-block serial
// scan that idled 255/256 CUs.
// ---------------------------------------------------------------------------
__global__ __launch_bounds__(256) void scatter_k(
    const int* __restrict__ tk_idx, const float* __restrict__ tk_w,
    const int* __restrict__ cnt, int* __restrict__ cursor,
    int* __restrict__ offs, int* __restrict__ slot_token,
    float* __restrict__ slot_w, int* __restrict__ slot_of)
{
  int pre[8]; int a = 0;
#pragma unroll
  for (int e = 0; e < 8; ++e) { pre[e] = a; a += cnt[e]; }
  const int idx = blockIdx.x * 256 + threadIdx.x;   // 0..8191
  const int e = tk_idx[idx];
  const int pos = atomicAdd(&cursor[e], 1);
  const int s = pre[e] + pos;
  slot_token[s] = idx >> 1;
  slot_w[s] = tk_w[idx];
  slot_of[idx] = s;
  if (blockIdx.x == 0 && threadIdx.x < 9)
    offs[threadIdx.x] = (threadIdx.x == 8) ? a : pre[threadIdx.x];
}

// ---------------------------------------------------------------------------
// GEMM (round-5 verified BK=64 geometry, full width): 256x256 tile, BK=64,
// 512 thr = 8 waves (2m x 4n), wave-tile 128x64. Single __syncthreads per
// K-step, double-buffered global_load_lds staging, XOR granule swizzle on
// both sides (conflicts measured 0). FC2 at this config measured 119.7us
// (best across 6 structural variants); BK64 > BK32 by 7%.
// STAGE 1: A=x_norm (z>0 gathered via slot_token), out = fast-GELU -> bf16.
// STAGE 2: A=hid (z>0 rows 4096+slot), out bf16 * (z==0 ? 1/9 : slot_w).
// ---------------------------------------------------------------------------
template <int N, int KD, int STAGE, int BK>
__global__ __launch_bounds__(512) void gemm2_k(
    const u16* __restrict__ Abase, const u16* __restrict__ Bsh,
    const u16* __restrict__ Bex, const float* __restrict__ bias_sh,
    const float* __restrict__ bias_ex,
    u16* __restrict__ outH,
    const int* __restrict__ offs, const int* __restrict__ slot_token,
    const float* __restrict__ slot_w, int nbase)
{
  constexpr int G    = BK / 8;          // 16B granules per row
  constexpr int CH   = BK / 16;         // staging chunks per matrix
  constexpr int RJ   = 512 / G;         // rows per chunk
  constexpr int TILE = 256 * BK;        // u16 per tile
  constexpr int KS   = BK / 32;         // MFMA k-slices per step

  const int tid = threadIdx.x;
  const int z = blockIdx.z;
  int off = 0, cnt = 4096, obase = 0;
  const u16* B = Bsh;
  const float* biasp = bias_sh;
  if (z > 0) {
    off = offs[z - 1]; cnt = offs[z] - off; obase = 4096 + off;
    B = Bex + (size_t)(z - 1) * N * KD;
    biasp = bias_ex + (size_t)(z - 1) * N;
  }
  const int m0 = blockIdx.y * 256;
  if (m0 >= cnt) return;
  const int n0 = nbase + blockIdx.x * 256;

  __shared__ u16 lds[2 * 2 * TILE];   // [buf][A|B][TILE]

  const int w = tid >> 6, l = tid & 63;

  // ---- staging geometry ----
  const int rth = tid / G;            // row-within-chunk
  const int pgt = tid % G;            // phys granule
  const int lg  = (BK == 64) ? (pgt ^ (rth & 7)) : (pgt ^ ((rth >> 1) & 3));

  const u16* gA[CH];
  const u16* gB[CH];
#pragma unroll
  for (int j = 0; j < CH; ++j) {
    int r = m0 + j * RJ + rth;
    if (r > cnt - 1) r = cnt - 1;
    size_t arow;
    if (STAGE == 1) arow = (z == 0) ? (size_t)r : (size_t)slot_token[off + r];
    else            arow = (z == 0) ? (size_t)r : (size_t)(4096 + off + r);
    gA[j] = Abase + arow * KD + lg * 8;
    gB[j] = B + (size_t)(n0 + j * RJ + rth) * KD + lg * 8;
  }

  // ---- MFMA geometry (16x16x32; C/D: col=lane&15, row=(lane>>4)*4+reg) ----
  const int wm = w >> 2, wn = w & 3;    // wave tile: rows wm*128.., cols wn*64..
  const int fr = l & 15, fq = l >> 4;
  const int swzm = (BK == 64) ? (fr & 7) : ((fr >> 1) & 3);
  const int rowA = (wm * 128 + fr) * BK;   // u16, A frag row base (mi=0)
  const int rowB = (wn * 64 + fr) * BK;    // u16, B frag row base (ni=0)

  f32x4 acc[8][4];
  const f32x4 zero = {0.f, 0.f, 0.f, 0.f};
#pragma unroll
  for (int mi = 0; mi < 8; ++mi)
#pragma unroll
    for (int ni = 0; ni < 4; ++ni) acc[mi][ni] = zero;

  const int NT = KD / BK;

#define STAGE_TILE(d)                                                       \
  { u16* dst = lds + (d) * 2 * TILE;                                        \
    _Pragma("unroll") for (int j = 0; j < CH; ++j) {                        \
      ASYNC_COPY16(gA[j], dst + j * 4096 + w * 512); gA[j] += BK; }         \
    _Pragma("unroll") for (int j = 0; j < CH; ++j) {                        \
      ASYNC_COPY16(gB[j], dst + TILE + j * 4096 + w * 512); gB[j] += BK; } }

  // prologue: tile 0 -> buf 0
  STAGE_TILE(0);

  for (int kb = 0; kb < NT; ++kb) {
    const int cur = kb & 1;
    __syncthreads();            // drains prefetch of cur; reads of cur^1 done
    if (kb + 1 < NT) { STAGE_TILE(cur ^ 1); }

    const u16* sA = lds + cur * 2 * TILE;
    const u16* sB = sA + TILE;
#pragma unroll
    for (int ks = 0; ks < KS; ++ks) {
      const int sw = (((ks * 4 + fq) ^ swzm)) * 8;
      bf16x8 af[8], bv[4];
#pragma unroll
      for (int mi = 0; mi < 8; ++mi) af[mi] = *(const bf16x8*)(sA + rowA + mi * 16 * BK + sw);
#pragma unroll
      for (int ni = 0; ni < 4; ++ni) bv[ni] = *(const bf16x8*)(sB + rowB + ni * 16 * BK + sw);
#pragma unroll
      for (int mi = 0; mi < 8; ++mi)
#pragma unroll
        for (int ni = 0; ni < 4; ++ni)
          acc[mi][ni] = __builtin_amdgcn_mfma_f32_16x16x32_bf16(af[mi], bv[ni], acc[mi][ni], 0, 0, 0);
    }
  }

  // epilogue: C/D layout col=lane&15, row=(lane>>4)*4+reg
#pragma unroll
  for (int mi = 0; mi < 8; ++mi) {
    const int mlBase = m0 + wm * 128 + mi * 16 + fq * 4;
#pragma unroll
    for (int r = 0; r < 4; ++r) {
      const int ml = mlBase + r;
      if (ml >= cnt) continue;
      const size_t orow = (size_t)(obase + ml) * N;
      float rwgt = (STAGE == 2) ? ((z == 0) ? (1.0f / 9.0f) : slot_w[off + ml]) : 1.f;
#pragma unroll
      for (int ni = 0; ni < 4; ++ni) {
        const int col = n0 + wn * 64 + ni * 16 + fr;
        float v = acc[mi][ni][r] + biasp[col];
        if (STAGE == 1) v = gelu_fast(v);
        else            v = v * rwgt;
        outH[orow + col] = f2bf(v);
      }
    }
  }
#undef STAGE_TILE
}

// ---------------------------------------------------------------------------
// K5: combine shared + 2 expert slots (bf16), then LayerNorm over O.
// ---------------------------------------------------------------------------
__global__ __launch_bounds__(256) void combine_ln2_k(
    const u16* __restrict__ sh_out, const u16* __restrict__ eout,
    const int* __restrict__ slot_of,
    const float* __restrict__ g2, const float* __restrict__ b2,
    float* __restrict__ out)
{
  const int t = blockIdx.x, tid = threadIdx.x;
  const int wave = tid >> 6, lane = tid & 63;
  __shared__ float red[8];
  const size_t s0 = (size_t)slot_of[2 * t], s1 = (size_t)slot_of[2 * t + 1];
  union { uint2 v; u16 h[4]; } a, c0, c1;
  a.v  = *(const uint2*)(sh_out + (size_t)t * 1024 + 4 * tid);
  c0.v = *(const uint2*)(eout + s0 * 1024 + 4 * tid);
  c1.v = *(const uint2*)(eout + s1 * 1024 + 4 * tid);
  float vv[4];
#pragma unroll
  for (int j = 0; j < 4; ++j) vv[j] = bf2f(a.h[j]) + bf2f(c0.h[j]) + bf2f(c1.h[j]);
  float s = vv[0] + vv[1] + vv[2] + vv[3];
  float q = vv[0] * vv[0] + vv[1] * vv[1] + vv[2] * vv[2] + vv[3] * vv[3];
#pragma unroll
  for (int o = 32; o > 0; o >>= 1) { s += __shfl_down(s, o, 64); q += __shfl_down(q, o, 64); }
  if (lane == 0) { red[wave] = s; red[4 + wave] = q; }
  __syncthreads();
  if (tid == 0) {
    float S = red[0] + red[1] + red[2] + red[3];
    float Q = red[4] + red[5] + red[6] + red[7];
    float mean = S * (1.0f / 1024.0f);
    float var = Q * (1.0f / 1024.0f) - mean * mean;
    red[0] = mean; red[1] = rsqrtf(var + 1e-5f);
  }
  __syncthreads();
  const float mean = red[0], rstd = red[1];
#pragma unroll
  for (int j = 0; j < 4; ++j) {
    int d = 4 * tid + j;
    out[(size_t)t * 1024 + d] = (vv[j] - mean) * rstd * g2[d] + b2[d];
  }
}

// ---------------------------------------------------------------------------
extern "C" void kernel_launch(void* const* d_in, const int* in_sizes, int n_in,
                              void* d_out, int out_size, void* d_ws, size_t ws_size,
                              hipStream_t stream)
{
  const float* x     = (const float*)d_in[0];
  const float* ln1_g = (const float*)d_in[1];
  const float* ln1_b = (const float*)d_in[2];
  const float* rw    = (const float*)d_in[3];
  const float* rb    = (const float*)d_in[4];
  const float* sh_w1 = (const float*)d_in[5];
  const float* sh_b1 = (const float*)d_in[6];
  const float* sh_w2 = (const float*)d_in[7];
  const float* sh_b2 = (const float*)d_in[8];
  const float* e_w1  = (const float*)d_in[9];
  const float* e_b1  = (const float*)d_in[10];
  const float* e_w2  = (const float*)d_in[11];
  const float* e_b2  = (const float*)d_in[12];
  const float* ln2_g = (const float*)d_in[13];
  const float* ln2_b = (const float*)d_in[14];
  float* out = (float*)d_out;

  char* w = (char*)d_ws;
  u16*   x_norm = (u16*)(w + 0);              //  8 MiB  [4096,1024] bf16
  u16*   hid    = (u16*)(w + (8u << 20));     // 48 MiB  [12288,2048] bf16 (shared|slots)
  u16*   outb   = (u16*)(w + (56u << 20));    // 24 MiB  [12288,1024] bf16 (shared|slots)
  u16*   w1b    = (u16*)(w + (104u << 20));   //  4 MiB  [2048,1024]  (contig with below)
  u16*   w2b    = (u16*)(w + (108u << 20));   //  4 MiB  [1024,2048]
  u16*   ew1b   = (u16*)(w + (112u << 20));   // 32 MiB  [8,2048,1024]
  u16*   ew2b   = (u16*)(w + (144u << 20));   // 32 MiB  [8,1024,2048]
  char*  meta   = w + (176u << 20);
  int*   tk_idx     = (int*)(meta);
  float* tk_w       = (float*)(meta + (32u << 10));
  int*   slot_token = (int*)(meta + (64u << 10));
  float* slot_w     = (float*)(meta + (96u << 10));
  int*   slot_of    = (int*)(meta + (128u << 10));
  int*   offs       = (int*)(meta + (160u << 10)); // 9 ints
  int*   cnt        = (int*)(meta + (192u << 10)); // 8 ints
  int*   cursor     = cnt + 8;                     // 8 ints

  // zero the per-expert count + cursor region (stream-ordered, capture-safe)
  hipMemsetAsync(cnt, 0, 16 * sizeof(int), stream);

  // fused: weight f32->bf16 conversion (blocks 4096..8703, grid-stride)
  //      + LayerNorm/router/top-2 + per-expert counts (blocks 0..4095)
  pre_fused_k<<<8704, 256, 0, stream>>>(
      x, ln1_g, ln1_b, rw, rb, x_norm, tk_idx, tk_w, cnt,
      sh_w1, sh_w2, e_w1, e_w2, w1b);

  // parallel slot assignment (order within expert segment is arbitrary)
  scatter_k<<<32, 256, 0, stream>>>(tk_idx, tk_w, cnt, cursor,
                                    offs, slot_token, slot_w, slot_of);

  // FC1 (shared z=0 + experts z=1..8): -> fast GELU -> hid bf16
  gemm2_k<2048, 1024, 1, 64><<<dim3(8, 16, 9), 512, 0, stream>>>(
      x_norm, w1b, ew1b, sh_b1, e_b1, hid, offs, slot_token, nullptr, 0);
  // FC2 (shared z=0 + experts z=1..8): -> scaled bf16 -> outb
  gemm2_k<1024, 2048, 2, 64><<<dim3(4, 16, 9), 512, 0, stream>>>(
      hid, w2b, ew2b, sh_b2, e_b2, outb, offs, slot_token, slot_w, 0);

  combine_ln2_k<<<4096, 256, 0, stream>>>(outb, outb + (size_t)4096 * 1024,
                                          slot_of, ln2_g, ln2_b, out);
}

// Round 7
// 530.393 us; speedup vs baseline: 1.0463x; 1.0463x over previous
//
#include <hip/hip_runtime.h>
#include <math.h>
#include <stdint.h>

typedef unsigned short u16;
typedef unsigned int u32;

typedef __attribute__((ext_vector_type(8))) short bf16x8;
typedef __attribute__((ext_vector_type(4))) float f32x4;

#define ASYNC_COPY16(g, l)                                                         \
  __builtin_amdgcn_global_load_lds((__attribute__((address_space(1))) const void*)(g), \
                                   (__attribute__((address_space(3))) void*)(l), 16, 0, 0)

__device__ __forceinline__ float bf2f(u16 u) {
  union { u32 i; float f; } v; v.i = ((u32)u) << 16; return v.f;
}
__device__ __forceinline__ u16 f2bf(float f) {
  union { float f; u32 i; } v; v.f = f;
  u32 r = v.i + 0x7fffu + ((v.i >> 16) & 1u);
  return (u16)(r >> 16);
}
// fast GELU (tanh form via sigmoid): x*sigmoid(1.5957691*(x+0.044715*x^3))
__device__ __forceinline__ float gelu_fast(float x) {
  float t = x * x;
  float z = 1.5957691f * x * (1.0f + 0.044715f * t);
  return x / (1.0f + __expf(-z));
}

// ---------------------------------------------------------------------------
// K1: LayerNorm(x) + router logits + top-2. One block per token. No atomics.
// (round-0/1 known-good version; round-6's fused/atomic variant regressed)
// ---------------------------------------------------------------------------
__global__ __launch_bounds__(256) void ln_router_k(
    const float* __restrict__ x, const float* __restrict__ g, const float* __restrict__ b,
    const float* __restrict__ rw, const float* __restrict__ rb,
    u16* __restrict__ xn, int* __restrict__ tk_idx, float* __restrict__ tk_w)
{
  const int t = blockIdx.x, tid = threadIdx.x;
  __shared__ float xs[1024];
  __shared__ float red[8];
  __shared__ float logits[8];
  const int wave = tid >> 6, lane = tid & 63;

  const float4 xv = *(const float4*)(x + (size_t)t * 1024 + 4 * tid);
  float v0 = xv.x, v1 = xv.y, v2 = xv.z, v3 = xv.w;
  float s = v0 + v1 + v2 + v3;
  float q = v0 * v0 + v1 * v1 + v2 * v2 + v3 * v3;
#pragma unroll
  for (int o = 32; o > 0; o >>= 1) { s += __shfl_down(s, o, 64); q += __shfl_down(q, o, 64); }
  if (lane == 0) { red[wave] = s; red[4 + wave] = q; }
  __syncthreads();
  if (tid == 0) {
    float S = red[0] + red[1] + red[2] + red[3];
    float Q = red[4] + red[5] + red[6] + red[7];
    float mean = S * (1.0f / 1024.0f);
    float var = Q * (1.0f / 1024.0f) - mean * mean;
    red[0] = mean; red[1] = rsqrtf(var + 1e-5f);
  }
  __syncthreads();
  const float mean = red[0], rstd = red[1];
  float vv[4] = {v0, v1, v2, v3};
  union { u16 h[4]; uint2 v; } pk;
#pragma unroll
  for (int j = 0; j < 4; ++j) {
    int d = 4 * tid + j;
    float y = (vv[j] - mean) * rstd * g[d] + b[d];
    xs[d] = y;
    pk.h[j] = f2bf(y);
  }
  *(uint2*)(xn + (size_t)t * 1024 + 4 * tid) = pk.v;
  __syncthreads();
#pragma unroll
  for (int pe = 0; pe < 2; ++pe) {
    int e = wave + 4 * pe;
    const float* wrow = rw + (size_t)e * 1024;
    float acc = 0.f;
#pragma unroll
    for (int j = 0; j < 16; ++j) {
      int d = lane + 64 * j;
      acc += xs[d] * wrow[d];
    }
#pragma unroll
    for (int o = 32; o > 0; o >>= 1) acc += __shfl_down(acc, o, 64);
    if (lane == 0) logits[e] = acc + rb[e];
  }
  __syncthreads();
  if (tid == 0) {
    int i0 = 0; float l0 = logits[0];
#pragma unroll
    for (int e = 1; e < 8; ++e) if (logits[e] > l0) { l0 = logits[e]; i0 = e; }
    int i1 = -1; float l1 = -3.4e38f;
#pragma unroll
    for (int e = 0; e < 8; ++e) { if (e == i0) continue; if (logits[e] > l1) { l1 = logits[e]; i1 = e; } }
    float w0 = 1.0f / (1.0f + expf(l1 - l0));
    float w1 = 1.0f - w0;
    tk_idx[2 * t] = i0; tk_idx[2 * t + 1] = i1;
    tk_w[2 * t] = w0; tk_w[2 * t + 1] = w1;
  }
}

// ---------------------------------------------------------------------------
// K2: single-block deterministic slot assignment (atomic-free, round-0).
// ---------------------------------------------------------------------------
__device__ __forceinline__ uint4 u4_add(uint4 a, uint4 b) {
  uint4 r; r.x = a.x + b.x; r.y = a.y + b.y; r.z = a.z + b.z; r.w = a.w + b.w; return r;
}
__device__ __forceinline__ uint4 u4_sub(uint4 a, uint4 b) {
  uint4 r; r.x = a.x - b.x; r.y = a.y - b.y; r.z = a.z - b.z; r.w = a.w - b.w; return r;
}

__global__ __launch_bounds__(256) void assign_k(
    const int* __restrict__ tk_idx, const float* __restrict__ tk_w,
    int* __restrict__ offs, int* __restrict__ slot_token,
    float* __restrict__ slot_w, int* __restrict__ slot_of)
{
  const int tid = threadIdx.x, lane = tid & 63, wave = tid >> 6;
  int eidx[32];
#pragma unroll
  for (int j = 0; j < 32; ++j) eidx[j] = tk_idx[tid * 32 + j];

  uint4 p = {0u, 0u, 0u, 0u};
#pragma unroll
  for (int j = 0; j < 32; ++j) {
    int e = eidx[j];
    unsigned inc = 1u << ((e & 1) * 16);
    int c = e >> 1;
    if (c == 0) p.x += inc; else if (c == 1) p.y += inc;
    else if (c == 2) p.z += inc; else p.w += inc;
  }
  const uint4 own = p;
#pragma unroll
  for (int o = 1; o < 64; o <<= 1) {
    uint4 t;
    t.x = (u32)__shfl_up((int)p.x, o, 64);
    t.y = (u32)__shfl_up((int)p.y, o, 64);
    t.z = (u32)__shfl_up((int)p.z, o, 64);
    t.w = (u32)__shfl_up((int)p.w, o, 64);
    if (lane >= o) p = u4_add(p, t);
  }
  __shared__ uint4 wtot[4];
  __shared__ int offs_s[9];
  if (lane == 63) wtot[wave] = p;
  __syncthreads();
  uint4 wbase = {0u, 0u, 0u, 0u};
  uint4 gtot = {0u, 0u, 0u, 0u};
#pragma unroll
  for (int w2 = 0; w2 < 4; ++w2) {
    uint4 t = wtot[w2];
    if (w2 < wave) wbase = u4_add(wbase, t);
    gtot = u4_add(gtot, t);
  }
  const uint4 excl = u4_sub(p, own);
  if (tid == 0) {
    int gtots[8] = { (int)(gtot.x & 0xffff), (int)(gtot.x >> 16),
                     (int)(gtot.y & 0xffff), (int)(gtot.y >> 16),
                     (int)(gtot.z & 0xffff), (int)(gtot.z >> 16),
                     (int)(gtot.w & 0xffff), (int)(gtot.w >> 16) };
    int a = 0;
#pragma unroll
    for (int e = 0; e < 8; ++e) { offs_s[e] = a; offs[e] = a; a += gtots[e]; }
    offs_s[8] = a; offs[8] = a;
  }
  __syncthreads();
  const uint4 pre = u4_add(wbase, excl);
  int base[8];
  base[0] = offs_s[0] + (int)(pre.x & 0xffff);
  base[1] = offs_s[1] + (int)(pre.x >> 16);
  base[2] = offs_s[2] + (int)(pre.y & 0xffff);
  base[3] = offs_s[3] + (int)(pre.y >> 16);
  base[4] = offs_s[4] + (int)(pre.z & 0xffff);
  base[5] = offs_s[5] + (int)(pre.z >> 16);
  base[6] = offs_s[6] + (int)(pre.w & 0xffff);
  base[7] = offs_s[7] + (int)(pre.w >> 16);
#pragma unroll
  for (int j = 0; j < 32; ++j) {
    int idx = tid * 32 + j;
    int e = eidx[j];
    int s = base[e]++;
    slot_token[s] = idx >> 1;
    slot_w[s] = tk_w[idx];
    slot_of[idx] = s;
  }
}

// ---------------------------------------------------------------------------
// Round-13 GEMM: 256x256 tile, BK=64, 512 thr = 8 waves (2m x 4n), wave-tile
// 128x64 -- the round-4/5 verified geometry -- with B STAGED DIRECTLY FROM
// F32 WEIGHTS (reg-staged: 2x float4 per chunk -> f2bf pack -> ds_write_b128
// into the SAME swizzled LDS layout). This deletes the separate cvt_all
// kernel entirely: net -150MB HBM (cvt read 216 + wrote 108; GEMMs add only
// +75MB/FC of f32 reads) and one less serialized launch. A stays bf16 via
// global_load_lds. Loop: single __syncthreads per K-step, double-buffered;
// B's reg->LDS write lands after the MFMA cluster (compiler inserts the
// vmcnt wait before first use of the loaded regs).
// LDS layout/swizzle per round-5 (conflicts measured 0): 16B granule, slot
// (row, pgt) holds logical granule pgt ^ (row&7); staging pre-swizzles the
// global source; read phys = (ks*4+fq) ^ (fr&7).
// STAGE 1: A=x_norm (z>0 gathered via slot_token), out = fast-GELU -> bf16.
// STAGE 2: A=hid (z>0 rows 4096+slot), out bf16 * (z==0 ? 1/9 : slot_w).
// ---------------------------------------------------------------------------
template <int N, int KD, int STAGE>
__global__ __launch_bounds__(512) void gemm3_k(
    const u16* __restrict__ Abase,
    const float* __restrict__ Bsh, const float* __restrict__ Bex,
    const float* __restrict__ bias_sh, const float* __restrict__ bias_ex,
    u16* __restrict__ outH,
    const int* __restrict__ offs, const int* __restrict__ slot_token,
    const float* __restrict__ slot_w)
{
  constexpr int BK   = 64;
  constexpr int TILE = 256 * BK;        // u16 per A-or-B tile (16384)

  const int tid = threadIdx.x;
  const int z = blockIdx.z;
  int off = 0, cnt = 4096, obase = 0;
  const float* B = Bsh;
  const float* biasp = bias_sh;
  if (z > 0) {
    off = offs[z - 1]; cnt = offs[z] - off; obase = 4096 + off;
    B = Bex + (size_t)(z - 1) * N * KD;
    biasp = bias_ex + (size_t)(z - 1) * N;
  }
  const int m0 = blockIdx.y * 256;
  if (m0 >= cnt) return;
  const int n0 = blockIdx.x * 256;

  __shared__ u16 lds[4 * TILE];   // [buf][A|B][TILE] = 128 KiB

  const int w = tid >> 6;

  // ---- staging geometry (BK=64: 8 granules/row, 4 chunks of 64 rows) ----
  const int rth = tid >> 3;            // row-within-chunk 0..63
  const int pgt = tid & 7;             // phys granule
  const int lg  = pgt ^ (rth & 7);     // logical granule (pre-swizzle)

  const u16*   gA[4];
  const float* gB[4];
#pragma unroll
  for (int j = 0; j < 4; ++j) {
    int r = m0 + j * 64 + rth;
    if (r > cnt - 1) r = cnt - 1;
    size_t arow;
    if (STAGE == 1) arow = (z == 0) ? (size_t)r : (size_t)slot_token[off + r];
    else            arow = (z == 0) ? (size_t)r : (size_t)(4096 + off + r);
    gA[j] = Abase + arow * KD + lg * 8;
    gB[j] = B + (size_t)(n0 + j * 64 + rth) * KD + lg * 8;
  }

  // ---- MFMA geometry (16x16x32; C/D: col=lane&15, row=(lane>>4)*4+reg) ----
  const int l = tid & 63;
  const int wm = w >> 2, wn = w & 3;    // wave tile: rows wm*128.., cols wn*64..
  const int fr = l & 15, fq = l >> 4;
  const int swzm = fr & 7;
  const int rowA = (wm * 128 + fr) * BK;   // u16, A frag row base (mi=0)
  const int rowB = (wn * 64 + fr) * BK;    // u16, B frag row base (ni=0)

  f32x4 acc[8][4];
  const f32x4 zero = {0.f, 0.f, 0.f, 0.f};
#pragma unroll
  for (int mi = 0; mi < 8; ++mi)
#pragma unroll
    for (int ni = 0; ni < 4; ++ni) acc[mi][ni] = zero;

  const int NT = KD / BK;

  float4 br[4][2];   // B f32 staging regs (32 floats)

#define STAGE_A3(d)                                                         \
  { u16* dst = lds + (d) * 2 * TILE;                                        \
    _Pragma("unroll") for (int j = 0; j < 4; ++j) {                         \
      ASYNC_COPY16(gA[j], dst + j * 4096 + w * 512); gA[j] += BK; } }
#define LOADB3                                                              \
  { _Pragma("unroll") for (int j = 0; j < 4; ++j) {                         \
      br[j][0] = *(const float4*)(gB[j]);                                   \
      br[j][1] = *(const float4*)(gB[j] + 4); gB[j] += BK; } }
#define WRITEB3(d)                                                          \
  { u16* dst = lds + (d) * 2 * TILE + TILE + tid * 8;                       \
    _Pragma("unroll") for (int j = 0; j < 4; ++j) {                         \
      union { u16 h[8]; uint4 v; } o;                                       \
      o.h[0] = f2bf(br[j][0].x); o.h[1] = f2bf(br[j][0].y);                 \
      o.h[2] = f2bf(br[j][0].z); o.h[3] = f2bf(br[j][0].w);                 \
      o.h[4] = f2bf(br[j][1].x); o.h[5] = f2bf(br[j][1].y);                 \
      o.h[6] = f2bf(br[j][1].z); o.h[7] = f2bf(br[j][1].w);                 \
      *(uint4*)(dst + j * 4096) = o.v; } }

  // prologue: tile 0 fully into buf 0
  STAGE_A3(0);
  LOADB3;
  WRITEB3(0);

  for (int kb = 0; kb < NT; ++kb) {
    const int cur = kb & 1;
    __syncthreads();   // buf[cur] complete & visible; reads of buf[cur^1] done
    if (kb + 1 < NT) {
      STAGE_A3(cur ^ 1);   // async A -> LDS (drained by next barrier)
      LOADB3;              // B f32 -> regs (in flight across MFMA section)
    }

    const u16* sA = lds + cur * 2 * TILE;
    const u16* sB = sA + TILE;
#pragma unroll
    for (int ks = 0; ks < 2; ++ks) {
      const int sw = (((ks * 4 + fq) ^ swzm)) * 8;
      bf16x8 af[8], bv[4];
#pragma unroll
      for (int mi = 0; mi < 8; ++mi) af[mi] = *(const bf16x8*)(sA + rowA + mi * 16 * BK + sw);
#pragma unroll
      for (int ni = 0; ni < 4; ++ni) bv[ni] = *(const bf16x8*)(sB + rowB + ni * 16 * BK + sw);
#pragma unroll
      for (int mi = 0; mi < 8; ++mi)
#pragma unroll
        for (int ni = 0; ni < 4; ++ni)
          acc[mi][ni] = __builtin_amdgcn_mfma_f32_16x16x32_bf16(af[mi], bv[ni], acc[mi][ni], 0, 0, 0);
    }

    if (kb + 1 < NT) { WRITEB3(cur ^ 1); }   // compiler waits vmcnt for br use
  }

  // epilogue: C/D layout col=lane&15, row=(lane>>4)*4+reg
#pragma unroll
  for (int mi = 0; mi < 8; ++mi) {
    const int mlBase = m0 + wm * 128 + mi * 16 + fq * 4;
#pragma unroll
    for (int r = 0; r < 4; ++r) {
      const int ml = mlBase + r;
      if (ml >= cnt) continue;
      const size_t orow = (size_t)(obase + ml) * N;
      float rwgt = (STAGE == 2) ? ((z == 0) ? (1.0f / 9.0f) : slot_w[off + ml]) : 1.f;
#pragma unroll
      for (int ni = 0; ni < 4; ++ni) {
        const int col = n0 + wn * 64 + ni * 16 + fr;
        float v = acc[mi][ni][r] + biasp[col];
        if (STAGE == 1) v = gelu_fast(v);
        else            v = v * rwgt;
        outH[orow + col] = f2bf(v);
      }
    }
  }
#undef STAGE_A3
#undef LOADB3
#undef WRITEB3
}

// ---------------------------------------------------------------------------
// K5: combine shared + 2 expert slots (bf16), then LayerNorm over O.
// ---------------------------------------------------------------------------
__global__ __launch_bounds__(256) void combine_ln2_k(
    const u16* __restrict__ sh_out, const u16* __restrict__ eout,
    const int* __restrict__ slot_of,
    const float* __restrict__ g2, const float* __restrict__ b2,
    float* __restrict__ out)
{
  const int t = blockIdx.x, tid = threadIdx.x;
  const int wave = tid >> 6, lane = tid & 63;
  __shared__ float red[8];
  const size_t s0 = (size_t)slot_of[2 * t], s1 = (size_t)slot_of[2 * t + 1];
  union { uint2 v; u16 h[4]; } a, c0, c1;
  a.v  = *(const uint2*)(sh_out + (size_t)t * 1024 + 4 * tid);
  c0.v = *(const uint2*)(eout + s0 * 1024 + 4 * tid);
  c1.v = *(const uint2*)(eout + s1 * 1024 + 4 * tid);
  float vv[4];
#pragma unroll
  for (int j = 0; j < 4; ++j) vv[j] = bf2f(a.h[j]) + bf2f(c0.h[j]) + bf2f(c1.h[j]);
  float s = vv[0] + vv[1] + vv[2] + vv[3];
  float q = vv[0] * vv[0] + vv[1] * vv[1] + vv[2] * vv[2] + vv[3] * vv[3];
#pragma unroll
  for (int o = 32; o > 0; o >>= 1) { s += __shfl_down(s, o, 64); q += __shfl_down(q, o, 64); }
  if (lane == 0) { red[wave] = s; red[4 + wave] = q; }
  __syncthreads();
  if (tid == 0) {
    float S = red[0] + red[1] + red[2] + red[3];
    float Q = red[4] + red[5] + red[6] + red[7];
    float mean = S * (1.0f / 1024.0f);
    float var = Q * (1.0f / 1024.0f) - mean * mean;
    red[0] = mean; red[1] = rsqrtf(var + 1e-5f);
  }
  __syncthreads();
  const float mean = red[0], rstd = red[1];
#pragma unroll
  for (int j = 0; j < 4; ++j) {
    int d = 4 * tid + j;
    out[(size_t)t * 1024 + d] = (vv[j] - mean) * rstd * g2[d] + b2[d];
  }
}

// ---------------------------------------------------------------------------
extern "C" void kernel_launch(void* const* d_in, const int* in_sizes, int n_in,
                              void* d_out, int out_size, void* d_ws, size_t ws_size,
                              hipStream_t stream)
{
  const float* x     = (const float*)d_in[0];
  const float* ln1_g = (const float*)d_in[1];
  const float* ln1_b = (const float*)d_in[2];
  const float* rw    = (const float*)d_in[3];
  const float* rb    = (const float*)d_in[4];
  const float* sh_w1 = (const float*)d_in[5];
  const float* sh_b1 = (const float*)d_in[6];
  const float* sh_w2 = (const float*)d_in[7];
  const float* sh_b2 = (const float*)d_in[8];
  const float* e_w1  = (const float*)d_in[9];
  const float* e_b1  = (const float*)d_in[10];
  const float* e_w2  = (const float*)d_in[11];
  const float* e_b2  = (const float*)d_in[12];
  const float* ln2_g = (const float*)d_in[13];
  const float* ln2_b = (const float*)d_in[14];
  float* out = (float*)d_out;

  char* w = (char*)d_ws;
  u16*   x_norm = (u16*)(w + 0);              //  8 MiB  [4096,1024] bf16
  u16*   hid    = (u16*)(w + (8u << 20));     // 48 MiB  [12288,2048] bf16 (shared|slots)
  u16*   outb   = (u16*)(w + (56u << 20));    // 24 MiB  [12288,1024] bf16 (shared|slots)
  char*  meta   = w + (176u << 20);
  int*   tk_idx     = (int*)(meta);
  float* tk_w       = (float*)(meta + (32u << 10));
  int*   slot_token = (int*)(meta + (64u << 10));
  float* slot_w     = (float*)(meta + (96u << 10));
  int*   slot_of    = (int*)(meta + (128u << 10));
  int*   offs       = (int*)(meta + (160u << 10)); // 9 ints

  ln_router_k<<<4096, 256, 0, stream>>>(x, ln1_g, ln1_b, rw, rb, x_norm, tk_idx, tk_w);
  assign_k<<<1, 256, 0, stream>>>(tk_idx, tk_w, offs, slot_token, slot_w, slot_of);

  // FC1 (shared z=0 + experts z=1..8): B = f32 weights directly -> GELU -> hid
  gemm3_k<2048, 1024, 1><<<dim3(8, 16, 9), 512, 0, stream>>>(
      x_norm, sh_w1, e_w1, sh_b1, e_b1, hid, offs, slot_token, nullptr);
  // FC2 (shared z=0 + experts z=1..8): B = f32 weights directly -> scaled -> outb
  gemm3_k<1024, 2048, 2><<<dim3(4, 16, 9), 512, 0, stream>>>(
      hid, sh_w2, e_w2, sh_b2, e_b2, outb, offs, slot_token, slot_w);

  combine_ln2_k<<<4096, 256, 0, stream>>>(outb, outb + (size_t)4096 * 1024,
                                          slot_of, ln2_g, ln2_b, out);
}

// Round 8
// 439.590 us; speedup vs baseline: 1.2624x; 1.2066x over previous
//
#include <hip/hip_runtime.h>
#include <math.h>
#include <stdint.h>

typedef unsigned short u16;
typedef unsigned int u32;

typedef __attribute__((ext_vector_type(8))) short bf16x8;
typedef __attribute__((ext_vector_type(4))) float f32x4;

#define ASYNC_COPY16(g, l)                                                         \
  __builtin_amdgcn_global_load_lds((__attribute__((address_space(1))) const void*)(g), \
                                   (__attribute__((address_space(3))) void*)(l), 16, 0, 0)

__device__ __forceinline__ float bf2f(u16 u) {
  union { u32 i; float f; } v; v.i = ((u32)u) << 16; return v.f;
}
__device__ __forceinline__ u16 f2bf(float f) {
  union { float f; u32 i; } v; v.f = f;
  u32 r = v.i + 0x7fffu + ((v.i >> 16) & 1u);
  return (u16)(r >> 16);
}
// fast GELU (tanh form via sigmoid): x*sigmoid(1.5957691*(x+0.044715*x^3))
__device__ __forceinline__ float gelu_fast(float x) {
  float t = x * x;
  float z = 1.5957691f * x * (1.0f + 0.044715f * t);
  return x / (1.0f + __expf(-z));
}

// ---------------------------------------------------------------------------
// K0: fused f32->bf16 conversion of all 4 weight tensors into ONE contiguous
// bf16 region (w1b | w2b | ew1b | ew2b). BW-bound (~324 MB total traffic);
// both in-GEMM conversion (R7) and block-range fusion (R6) measured worse.
// ---------------------------------------------------------------------------
__global__ __launch_bounds__(256) void cvt_all_k(
    const float* __restrict__ s0, const float* __restrict__ s1,
    const float* __restrict__ s2, const float* __restrict__ s3,
    u16* __restrict__ dst)
{
  const int64_t i0 = (int64_t)blockIdx.x * 2048 + (int64_t)threadIdx.x * 8;
  const float* src; int64_t rel;
  if (i0 < 2097152)       { src = s0; rel = i0; }
  else if (i0 < 4194304)  { src = s1; rel = i0 - 2097152; }
  else if (i0 < 20971520) { src = s2; rel = i0 - 4194304; }
  else                    { src = s3; rel = i0 - 20971520; }
  const float4 a = *(const float4*)(src + rel);
  const float4 b = *(const float4*)(src + rel + 4);
  union { u16 h[8]; uint4 v; } o;
  o.h[0] = f2bf(a.x); o.h[1] = f2bf(a.y); o.h[2] = f2bf(a.z); o.h[3] = f2bf(a.w);
  o.h[4] = f2bf(b.x); o.h[5] = f2bf(b.y); o.h[6] = f2bf(b.z); o.h[7] = f2bf(b.w);
  *(uint4*)(dst + i0) = o.v;
}

// ---------------------------------------------------------------------------
// K1: LayerNorm(x) + router logits + top-2. One block per token. No atomics.
// ---------------------------------------------------------------------------
__global__ __launch_bounds__(256) void ln_router_k(
    const float* __restrict__ x, const float* __restrict__ g, const float* __restrict__ b,
    const float* __restrict__ rw, const float* __restrict__ rb,
    u16* __restrict__ xn, int* __restrict__ tk_idx, float* __restrict__ tk_w)
{
  const int t = blockIdx.x, tid = threadIdx.x;
  __shared__ float xs[1024];
  __shared__ float red[8];
  __shared__ float logits[8];
  const int wave = tid >> 6, lane = tid & 63;

  const float4 xv = *(const float4*)(x + (size_t)t * 1024 + 4 * tid);
  float v0 = xv.x, v1 = xv.y, v2 = xv.z, v3 = xv.w;
  float s = v0 + v1 + v2 + v3;
  float q = v0 * v0 + v1 * v1 + v2 * v2 + v3 * v3;
#pragma unroll
  for (int o = 32; o > 0; o >>= 1) { s += __shfl_down(s, o, 64); q += __shfl_down(q, o, 64); }
  if (lane == 0) { red[wave] = s; red[4 + wave] = q; }
  __syncthreads();
  if (tid == 0) {
    float S = red[0] + red[1] + red[2] + red[3];
    float Q = red[4] + red[5] + red[6] + red[7];
    float mean = S * (1.0f / 1024.0f);
    float var = Q * (1.0f / 1024.0f) - mean * mean;
    red[0] = mean; red[1] = rsqrtf(var + 1e-5f);
  }
  __syncthreads();
  const float mean = red[0], rstd = red[1];
  float vv[4] = {v0, v1, v2, v3};
  union { u16 h[4]; uint2 v; } pk;
#pragma unroll
  for (int j = 0; j < 4; ++j) {
    int d = 4 * tid + j;
    float y = (vv[j] - mean) * rstd * g[d] + b[d];
    xs[d] = y;
    pk.h[j] = f2bf(y);
  }
  *(uint2*)(xn + (size_t)t * 1024 + 4 * tid) = pk.v;
  __syncthreads();
#pragma unroll
  for (int pe = 0; pe < 2; ++pe) {
    int e = wave + 4 * pe;
    const float* wrow = rw + (size_t)e * 1024;
    float acc = 0.f;
#pragma unroll
    for (int j = 0; j < 16; ++j) {
      int d = lane + 64 * j;
      acc += xs[d] * wrow[d];
    }
#pragma unroll
    for (int o = 32; o > 0; o >>= 1) acc += __shfl_down(acc, o, 64);
    if (lane == 0) logits[e] = acc + rb[e];
  }
  __syncthreads();
  if (tid == 0) {
    int i0 = 0; float l0 = logits[0];
#pragma unroll
    for (int e = 1; e < 8; ++e) if (logits[e] > l0) { l0 = logits[e]; i0 = e; }
    int i1 = -1; float l1 = -3.4e38f;
#pragma unroll
    for (int e = 0; e < 8; ++e) { if (e == i0) continue; if (logits[e] > l1) { l1 = logits[e]; i1 = e; } }
    float w0 = 1.0f / (1.0f + expf(l1 - l0));
    float w1 = 1.0f - w0;
    tk_idx[2 * t] = i0; tk_idx[2 * t + 1] = i1;
    tk_w[2 * t] = w0; tk_w[2 * t + 1] = w1;
  }
}

// ---------------------------------------------------------------------------
// K2: single-block deterministic slot assignment (atomic-free).
// ---------------------------------------------------------------------------
__device__ __forceinline__ uint4 u4_add(uint4 a, uint4 b) {
  uint4 r; r.x = a.x + b.x; r.y = a.y + b.y; r.z = a.z + b.z; r.w = a.w + b.w; return r;
}
__device__ __forceinline__ uint4 u4_sub(uint4 a, uint4 b) {
  uint4 r; r.x = a.x - b.x; r.y = a.y - b.y; r.z = a.z - b.z; r.w = a.w - b.w; return r;
}

__global__ __launch_bounds__(256) void assign_k(
    const int* __restrict__ tk_idx, const float* __restrict__ tk_w,
    int* __restrict__ offs, int* __restrict__ slot_token,
    float* __restrict__ slot_w, int* __restrict__ slot_of)
{
  const int tid = threadIdx.x, lane = tid & 63, wave = tid >> 6;
  int eidx[32];
#pragma unroll
  for (int j = 0; j < 32; ++j) eidx[j] = tk_idx[tid * 32 + j];

  uint4 p = {0u, 0u, 0u, 0u};
#pragma unroll
  for (int j = 0; j < 32; ++j) {
    int e = eidx[j];
    unsigned inc = 1u << ((e & 1) * 16);
    int c = e >> 1;
    if (c == 0) p.x += inc; else if (c == 1) p.y += inc;
    else if (c == 2) p.z += inc; else p.w += inc;
  }
  const uint4 own = p;
#pragma unroll
  for (int o = 1; o < 64; o <<= 1) {
    uint4 t;
    t.x = (u32)__shfl_up((int)p.x, o, 64);
    t.y = (u32)__shfl_up((int)p.y, o, 64);
    t.z = (u32)__shfl_up((int)p.z, o, 64);
    t.w = (u32)__shfl_up((int)p.w, o, 64);
    if (lane >= o) p = u4_add(p, t);
  }
  __shared__ uint4 wtot[4];
  __shared__ int offs_s[9];
  if (lane == 63) wtot[wave] = p;
  __syncthreads();
  uint4 wbase = {0u, 0u, 0u, 0u};
  uint4 gtot = {0u, 0u, 0u, 0u};
#pragma unroll
  for (int w2 = 0; w2 < 4; ++w2) {
    uint4 t = wtot[w2];
    if (w2 < wave) wbase = u4_add(wbase, t);
    gtot = u4_add(gtot, t);
  }
  const uint4 excl = u4_sub(p, own);
  if (tid == 0) {
    int gtots[8] = { (int)(gtot.x & 0xffff), (int)(gtot.x >> 16),
                     (int)(gtot.y & 0xffff), (int)(gtot.y >> 16),
                     (int)(gtot.z & 0xffff), (int)(gtot.z >> 16),
                     (int)(gtot.w & 0xffff), (int)(gtot.w >> 16) };
    int a = 0;
#pragma unroll
    for (int e = 0; e < 8; ++e) { offs_s[e] = a; offs[e] = a; a += gtots[e]; }
    offs_s[8] = a; offs[8] = a;
  }
  __syncthreads();
  const uint4 pre = u4_add(wbase, excl);
  int base[8];
  base[0] = offs_s[0] + (int)(pre.x & 0xffff);
  base[1] = offs_s[1] + (int)(pre.x >> 16);
  base[2] = offs_s[2] + (int)(pre.y & 0xffff);
  base[3] = offs_s[3] + (int)(pre.y >> 16);
  base[4] = offs_s[4] + (int)(pre.z & 0xffff);
  base[5] = offs_s[5] + (int)(pre.z >> 16);
  base[6] = offs_s[6] + (int)(pre.w & 0xffff);
  base[7] = offs_s[7] + (int)(pre.w >> 16);
#pragma unroll
  for (int j = 0; j < 32; ++j) {
    int idx = tid * 32 + j;
    int e = eidx[j];
    int s = base[e]++;
    slot_token[s] = idx >> 1;
    slot_w[s] = tk_w[idx];
    slot_of[idx] = s;
  }
}

// ---------------------------------------------------------------------------
// GEMM: measured-best config (round-5): 256x256 tile, BK=64, 512 thr =
// 8 waves (2m x 4n), wave-tile 128x64. Single __syncthreads per K-step,
// double-buffered global_load_lds staging, XOR granule swizzle on both
// sides (conflicts measured 0). FC2 at this exact config measured 119.7us
// -- best across 7 structural variants (128^2 2-phase=124, 8-phase=126-143,
// BK32=129, f32-direct-B=200).
// STAGE 1: A=x_norm (z>0 gathered via slot_token), out = fast-GELU -> bf16.
// STAGE 2: A=hid (z>0 rows 4096+slot), out bf16 * (z==0 ? 1/9 : slot_w).
// ---------------------------------------------------------------------------
template <int N, int KD, int STAGE>
__global__ __launch_bounds__(512) void gemm2_k(
    const u16* __restrict__ Abase, const u16* __restrict__ Bsh,
    const u16* __restrict__ Bex, const float* __restrict__ bias_sh,
    const float* __restrict__ bias_ex,
    u16* __restrict__ outH,
    const int* __restrict__ offs, const int* __restrict__ slot_token,
    const float* __restrict__ slot_w)
{
  constexpr int BK   = 64;
  constexpr int TILE = 256 * BK;        // u16 per A-or-B tile (16384)

  const int tid = threadIdx.x;
  const int z = blockIdx.z;
  int off = 0, cnt = 4096, obase = 0;
  const u16* B = Bsh;
  const float* biasp = bias_sh;
  if (z > 0) {
    off = offs[z - 1]; cnt = offs[z] - off; obase = 4096 + off;
    B = Bex + (size_t)(z - 1) * N * KD;
    biasp = bias_ex + (size_t)(z - 1) * N;
  }
  const int m0 = blockIdx.y * 256;
  if (m0 >= cnt) return;
  const int n0 = blockIdx.x * 256;

  __shared__ u16 lds[4 * TILE];   // [buf][A|B][TILE] = 128 KiB

  const int w = tid >> 6, l = tid & 63;

  // ---- staging geometry (8 granules/row, 4 chunks of 64 rows each) ----
  const int rth = tid >> 3;            // row-within-chunk 0..63
  const int pgt = tid & 7;             // phys granule
  const int lg  = pgt ^ (rth & 7);     // logical granule (pre-swizzle)

  const u16* gA[4];
  const u16* gB[4];
#pragma unroll
  for (int j = 0; j < 4; ++j) {
    int r = m0 + j * 64 + rth;
    if (r > cnt - 1) r = cnt - 1;
    size_t arow;
    if (STAGE == 1) arow = (z == 0) ? (size_t)r : (size_t)slot_token[off + r];
    else            arow = (z == 0) ? (size_t)r : (size_t)(4096 + off + r);
    gA[j] = Abase + arow * KD + lg * 8;
    gB[j] = B + (size_t)(n0 + j * 64 + rth) * KD + lg * 8;
  }

  // ---- MFMA geometry (16x16x32; C/D: col=lane&15, row=(lane>>4)*4+reg) ----
  const int wm = w >> 2, wn = w & 3;    // wave tile: rows wm*128.., cols wn*64..
  const int fr = l & 15, fq = l >> 4;
  const int swzm = fr & 7;
  const int rowA = (wm * 128 + fr) * BK;   // u16, A frag row base (mi=0)
  const int rowB = (wn * 64 + fr) * BK;    // u16, B frag row base (ni=0)

  f32x4 acc[8][4];
  const f32x4 zero = {0.f, 0.f, 0.f, 0.f};
#pragma unroll
  for (int mi = 0; mi < 8; ++mi)
#pragma unroll
    for (int ni = 0; ni < 4; ++ni) acc[mi][ni] = zero;

  const int NT = KD / BK;

#define STAGE_TILE(d)                                                       \
  { u16* dst = lds + (d) * 2 * TILE;                                        \
    _Pragma("unroll") for (int j = 0; j < 4; ++j) {                         \
      ASYNC_COPY16(gA[j], dst + j * 4096 + w * 512); gA[j] += BK; }         \
    _Pragma("unroll") for (int j = 0; j < 4; ++j) {                         \
      ASYNC_COPY16(gB[j], dst + TILE + j * 4096 + w * 512); gB[j] += BK; } }

  // prologue: tile 0 -> buf 0
  STAGE_TILE(0);

  for (int kb = 0; kb < NT; ++kb) {
    const int cur = kb & 1;
    __syncthreads();            // drains prefetch of cur; reads of cur^1 done
    if (kb + 1 < NT) { STAGE_TILE(cur ^ 1); }

    const u16* sA = lds + cur * 2 * TILE;
    const u16* sB = sA + TILE;
#pragma unroll
    for (int ks = 0; ks < 2; ++ks) {
      const int sw = (((ks * 4 + fq) ^ swzm)) * 8;
      bf16x8 af[8], bv[4];
#pragma unroll
      for (int mi = 0; mi < 8; ++mi) af[mi] = *(const bf16x8*)(sA + rowA + mi * 16 * BK + sw);
#pragma unroll
      for (int ni = 0; ni < 4; ++ni) bv[ni] = *(const bf16x8*)(sB + rowB + ni * 16 * BK + sw);
#pragma unroll
      for (int mi = 0; mi < 8; ++mi)
#pragma unroll
        for (int ni = 0; ni < 4; ++ni)
          acc[mi][ni] = __builtin_amdgcn_mfma_f32_16x16x32_bf16(af[mi], bv[ni], acc[mi][ni], 0, 0, 0);
    }
  }

  // epilogue: C/D layout col=lane&15, row=(lane>>4)*4+reg
#pragma unroll
  for (int mi = 0; mi < 8; ++mi) {
    const int mlBase = m0 + wm * 128 + mi * 16 + fq * 4;
#pragma unroll
    for (int r = 0; r < 4; ++r) {
      const int ml = mlBase + r;
      if (ml >= cnt) continue;
      const size_t orow = (size_t)(obase + ml) * N;
      float rwgt = (STAGE == 2) ? ((z == 0) ? (1.0f / 9.0f) : slot_w[off + ml]) : 1.f;
#pragma unroll
      for (int ni = 0; ni < 4; ++ni) {
        const int col = n0 + wn * 64 + ni * 16 + fr;
        float v = acc[mi][ni][r] + biasp[col];
        if (STAGE == 1) v = gelu_fast(v);
        else            v = v * rwgt;
        outH[orow + col] = f2bf(v);
      }
    }
  }
#undef STAGE_TILE
}

// ---------------------------------------------------------------------------
// K5: combine shared + 2 expert slots (bf16), then LayerNorm over O.
// ---------------------------------------------------------------------------
__global__ __launch_bounds__(256) void combine_ln2_k(
    const u16* __restrict__ sh_out, const u16* __restrict__ eout,
    const int* __restrict__ slot_of,
    const float* __restrict__ g2, const float* __restrict__ b2,
    float* __restrict__ out)
{
  const int t = blockIdx.x, tid = threadIdx.x;
  const int wave = tid >> 6, lane = tid & 63;
  __shared__ float red[8];
  const size_t s0 = (size_t)slot_of[2 * t], s1 = (size_t)slot_of[2 * t + 1];
  union { uint2 v; u16 h[4]; } a, c0, c1;
  a.v  = *(const uint2*)(sh_out + (size_t)t * 1024 + 4 * tid);
  c0.v = *(const uint2*)(eout + s0 * 1024 + 4 * tid);
  c1.v = *(const uint2*)(eout + s1 * 1024 + 4 * tid);
  float vv[4];
#pragma unroll
  for (int j = 0; j < 4; ++j) vv[j] = bf2f(a.h[j]) + bf2f(c0.h[j]) + bf2f(c1.h[j]);
  float s = vv[0] + vv[1] + vv[2] + vv[3];
  float q = vv[0] * vv[0] + vv[1] * vv[1] + vv[2] * vv[2] + vv[3] * vv[3];
#pragma unroll
  for (int o = 32; o > 0; o >>= 1) { s += __shfl_down(s, o, 64); q += __shfl_down(q, o, 64); }
  if (lane == 0) { red[wave] = s; red[4 + wave] = q; }
  __syncthreads();
  if (tid == 0) {
    float S = red[0] + red[1] + red[2] + red[3];
    float Q = red[4] + red[5] + red[6] + red[7];
    float mean = S * (1.0f / 1024.0f);
    float var = Q * (1.0f / 1024.0f) - mean * mean;
    red[0] = mean; red[1] = rsqrtf(var + 1e-5f);
  }
  __syncthreads();
  const float mean = red[0], rstd = red[1];
#pragma unroll
  for (int j = 0; j < 4; ++j) {
    int d = 4 * tid + j;
    out[(size_t)t * 1024 + d] = (vv[j] - mean) * rstd * g2[d] + b2[d];
  }
}

// ---------------------------------------------------------------------------
extern "C" void kernel_launch(void* const* d_in, const int* in_sizes, int n_in,
                              void* d_out, int out_size, void* d_ws, size_t ws_size,
                              hipStream_t stream)
{
  const float* x     = (const float*)d_in[0];
  const float* ln1_g = (const float*)d_in[1];
  const float* ln1_b = (const float*)d_in[2];
  const float* rw    = (const float*)d_in[3];
  const float* rb    = (const float*)d_in[4];
  const float* sh_w1 = (const float*)d_in[5];
  const float* sh_b1 = (const float*)d_in[6];
  const float* sh_w2 = (const float*)d_in[7];
  const float* sh_b2 = (const float*)d_in[8];
  const float* e_w1  = (const float*)d_in[9];
  const float* e_b1  = (const float*)d_in[10];
  const float* e_w2  = (const float*)d_in[11];
  const float* e_b2  = (const float*)d_in[12];
  const float* ln2_g = (const float*)d_in[13];
  const float* ln2_b = (const float*)d_in[14];
  float* out = (float*)d_out;

  char* w = (char*)d_ws;
  u16*   x_norm = (u16*)(w + 0);              //  8 MiB  [4096,1024] bf16
  u16*   hid    = (u16*)(w + (8u << 20));     // 48 MiB  [12288,2048] bf16 (shared|slots)
  u16*   outb   = (u16*)(w + (56u << 20));    // 24 MiB  [12288,1024] bf16 (shared|slots)
  u16*   w1b    = (u16*)(w + (104u << 20));   //  4 MiB  [2048,1024]  (contig with below)
  u16*   w2b    = (u16*)(w + (108u << 20));   //  4 MiB  [1024,2048]
  u16*   ew1b   = (u16*)(w + (112u << 20));   // 32 MiB  [8,2048,1024]
  u16*   ew2b   = (u16*)(w + (144u << 20));   // 32 MiB  [8,1024,2048]
  char*  meta   = w + (176u << 20);
  int*   tk_idx     = (int*)(meta);
  float* tk_w       = (float*)(meta + (32u << 10));
  int*   slot_token = (int*)(meta + (64u << 10));
  float* slot_w     = (float*)(meta + (96u << 10));
  int*   slot_of    = (int*)(meta + (128u << 10));
  int*   offs       = (int*)(meta + (160u << 10)); // 9 ints

  // all weights f32 -> bf16 in one pass (dsts are contiguous from w1b)
  cvt_all_k<<<18432, 256, 0, stream>>>(sh_w1, sh_w2, e_w1, e_w2, w1b);

  ln_router_k<<<4096, 256, 0, stream>>>(x, ln1_g, ln1_b, rw, rb, x_norm, tk_idx, tk_w);
  assign_k<<<1, 256, 0, stream>>>(tk_idx, tk_w, offs, slot_token, slot_w, slot_of);

  // FC1 (shared z=0 + experts z=1..8): -> fast GELU -> hid bf16
  gemm2_k<2048, 1024, 1><<<dim3(8, 16, 9), 512, 0, stream>>>(
      x_norm, w1b, ew1b, sh_b1, e_b1, hid, offs, slot_token, nullptr);
  // FC2 (shared z=0 + experts z=1..8): -> scaled bf16 -> outb
  gemm2_k<1024, 2048, 2><<<dim3(4, 16, 9), 512, 0, stream>>>(
      hid, w2b, ew2b, sh_b2, e_b2, outb, offs, slot_token, slot_w);

  combine_ln2_k<<<4096, 256, 0, stream>>>(outb, outb + (size_t)4096 * 1024,
                                          slot_of, ln2_g, ln2_b, out);
}

// Round 9
// 430.253 us; speedup vs baseline: 1.2898x; 1.0217x over previous
//
#include <hip/hip_runtime.h>
#include <math.h>
#include <stdint.h>

typedef unsigned short u16;
typedef unsigned int u32;

typedef __attribute__((ext_vector_type(8))) short bf16x8;
typedef __attribute__((ext_vector_type(4))) float f32x4;

#define ASYNC_COPY16(g, l)                                                         \
  __builtin_amdgcn_global_load_lds((__attribute__((address_space(1))) const void*)(g), \
                                   (__attribute__((address_space(3))) void*)(l), 16, 0, 0)

__device__ __forceinline__ float bf2f(u16 u) {
  union { u32 i; float f; } v; v.i = ((u32)u) << 16; return v.f;
}
__device__ __forceinline__ u16 f2bf(float f) {
  union { float f; u32 i; } v; v.f = f;
  u32 r = v.i + 0x7fffu + ((v.i >> 16) & 1u);
  return (u16)(r >> 16);
}
// fast GELU (tanh form via sigmoid): x*sigmoid(1.5957691*(x+0.044715*x^3))
__device__ __forceinline__ float gelu_fast(float x) {
  float t = x * x;
  float z = 1.5957691f * x * (1.0f + 0.044715f * t);
  return x / (1.0f + __expf(-z));
}

// ---------------------------------------------------------------------------
// K0: f32->bf16 conversion of the FC1 weights only (sh_w1 | e_w1 -> w1b|ew1b,
// contiguous 18M elems). FC2 weights are converted INSIDE the FC1 GEMM
// dispatch by its trailing z-slices (overlaps FC1's idle BW + tail CUs).
// ---------------------------------------------------------------------------
__global__ __launch_bounds__(256) void cvt1_k(
    const float* __restrict__ s0, const float* __restrict__ s1,
    u16* __restrict__ dst)
{
  const int64_t i0 = (int64_t)blockIdx.x * 2048 + (int64_t)threadIdx.x * 8;
  const float* src; int64_t rel;
  if (i0 < 2097152) { src = s0; rel = i0; }
  else              { src = s1; rel = i0 - 2097152; }
  const float4 a = *(const float4*)(src + rel);
  const float4 b = *(const float4*)(src + rel + 4);
  union { u16 h[8]; uint4 v; } o;
  o.h[0] = f2bf(a.x); o.h[1] = f2bf(a.y); o.h[2] = f2bf(a.z); o.h[3] = f2bf(a.w);
  o.h[4] = f2bf(b.x); o.h[5] = f2bf(b.y); o.h[6] = f2bf(b.z); o.h[7] = f2bf(b.w);
  *(uint4*)(dst + i0) = o.v;
}

// ---------------------------------------------------------------------------
// K1: LayerNorm(x) + router logits + top-2. One block per token. No atomics.
// ---------------------------------------------------------------------------
__global__ __launch_bounds__(256) void ln_router_k(
    const float* __restrict__ x, const float* __restrict__ g, const float* __restrict__ b,
    const float* __restrict__ rw, const float* __restrict__ rb,
    u16* __restrict__ xn, int* __restrict__ tk_idx, float* __restrict__ tk_w)
{
  const int t = blockIdx.x, tid = threadIdx.x;
  __shared__ float xs[1024];
  __shared__ float red[8];
  __shared__ float logits[8];
  const int wave = tid >> 6, lane = tid & 63;

  const float4 xv = *(const float4*)(x + (size_t)t * 1024 + 4 * tid);
  float v0 = xv.x, v1 = xv.y, v2 = xv.z, v3 = xv.w;
  float s = v0 + v1 + v2 + v3;
  float q = v0 * v0 + v1 * v1 + v2 * v2 + v3 * v3;
#pragma unroll
  for (int o = 32; o > 0; o >>= 1) { s += __shfl_down(s, o, 64); q += __shfl_down(q, o, 64); }
  if (lane == 0) { red[wave] = s; red[4 + wave] = q; }
  __syncthreads();
  if (tid == 0) {
    float S = red[0] + red[1] + red[2] + red[3];
    float Q = red[4] + red[5] + red[6] + red[7];
    float mean = S * (1.0f / 1024.0f);
    float var = Q * (1.0f / 1024.0f) - mean * mean;
    red[0] = mean; red[1] = rsqrtf(var + 1e-5f);
  }
  __syncthreads();
  const float mean = red[0], rstd = red[1];
  float vv[4] = {v0, v1, v2, v3};
  union { u16 h[4]; uint2 v; } pk;
#pragma unroll
  for (int j = 0; j < 4; ++j) {
    int d = 4 * tid + j;
    float y = (vv[j] - mean) * rstd * g[d] + b[d];
    xs[d] = y;
    pk.h[j] = f2bf(y);
  }
  *(uint2*)(xn + (size_t)t * 1024 + 4 * tid) = pk.v;
  __syncthreads();
#pragma unroll
  for (int pe = 0; pe < 2; ++pe) {
    int e = wave + 4 * pe;
    const float* wrow = rw + (size_t)e * 1024;
    float acc = 0.f;
#pragma unroll
    for (int j = 0; j < 16; ++j) {
      int d = lane + 64 * j;
      acc += xs[d] * wrow[d];
    }
#pragma unroll
    for (int o = 32; o > 0; o >>= 1) acc += __shfl_down(acc, o, 64);
    if (lane == 0) logits[e] = acc + rb[e];
  }
  __syncthreads();
  if (tid == 0) {
    int i0 = 0; float l0 = logits[0];
#pragma unroll
    for (int e = 1; e < 8; ++e) if (logits[e] > l0) { l0 = logits[e]; i0 = e; }
    int i1 = -1; float l1 = -3.4e38f;
#pragma unroll
    for (int e = 0; e < 8; ++e) { if (e == i0) continue; if (logits[e] > l1) { l1 = logits[e]; i1 = e; } }
    float w0 = 1.0f / (1.0f + expf(l1 - l0));
    float w1 = 1.0f - w0;
    tk_idx[2 * t] = i0; tk_idx[2 * t + 1] = i1;
    tk_w[2 * t] = w0; tk_w[2 * t + 1] = w1;
  }
}

// ---------------------------------------------------------------------------
// K2: single-block deterministic slot assignment (atomic-free).
// ---------------------------------------------------------------------------
__device__ __forceinline__ uint4 u4_add(uint4 a, uint4 b) {
  uint4 r; r.x = a.x + b.x; r.y = a.y + b.y; r.z = a.z + b.z; r.w = a.w + b.w; return r;
}
__device__ __forceinline__ uint4 u4_sub(uint4 a, uint4 b) {
  uint4 r; r.x = a.x - b.x; r.y = a.y - b.y; r.z = a.z - b.z; r.w = a.w - b.w; return r;
}

__global__ __launch_bounds__(256) void assign_k(
    const int* __restrict__ tk_idx, const float* __restrict__ tk_w,
    int* __restrict__ offs, int* __restrict__ slot_token,
    float* __restrict__ slot_w, int* __restrict__ slot_of)
{
  const int tid = threadIdx.x, lane = tid & 63, wave = tid >> 6;
  int eidx[32];
#pragma unroll
  for (int j = 0; j < 32; ++j) eidx[j] = tk_idx[tid * 32 + j];

  uint4 p = {0u, 0u, 0u, 0u};
#pragma unroll
  for (int j = 0; j < 32; ++j) {
    int e = eidx[j];
    unsigned inc = 1u << ((e & 1) * 16);
    int c = e >> 1;
    if (c == 0) p.x += inc; else if (c == 1) p.y += inc;
    else if (c == 2) p.z += inc; else p.w += inc;
  }
  const uint4 own = p;
#pragma unroll
  for (int o = 1; o < 64; o <<= 1) {
    uint4 t;
    t.x = (u32)__shfl_up((int)p.x, o, 64);
    t.y = (u32)__shfl_up((int)p.y, o, 64);
    t.z = (u32)__shfl_up((int)p.z, o, 64);
    t.w = (u32)__shfl_up((int)p.w, o, 64);
    if (lane >= o) p = u4_add(p, t);
  }
  __shared__ uint4 wtot[4];
  __shared__ int offs_s[9];
  if (lane == 63) wtot[wave] = p;
  __syncthreads();
  uint4 wbase = {0u, 0u, 0u, 0u};
  uint4 gtot = {0u, 0u, 0u, 0u};
#pragma unroll
  for (int w2 = 0; w2 < 4; ++w2) {
    uint4 t = wtot[w2];
    if (w2 < wave) wbase = u4_add(wbase, t);
    gtot = u4_add(gtot, t);
  }
  const uint4 excl = u4_sub(p, own);
  if (tid == 0) {
    int gtots[8] = { (int)(gtot.x & 0xffff), (int)(gtot.x >> 16),
                     (int)(gtot.y & 0xffff), (int)(gtot.y >> 16),
                     (int)(gtot.z & 0xffff), (int)(gtot.z >> 16),
                     (int)(gtot.w & 0xffff), (int)(gtot.w >> 16) };
    int a = 0;
#pragma unroll
    for (int e = 0; e < 8; ++e) { offs_s[e] = a; offs[e] = a; a += gtots[e]; }
    offs_s[8] = a; offs[8] = a;
  }
  __syncthreads();
  const uint4 pre = u4_add(wbase, excl);
  int base[8];
  base[0] = offs_s[0] + (int)(pre.x & 0xffff);
  base[1] = offs_s[1] + (int)(pre.x >> 16);
  base[2] = offs_s[2] + (int)(pre.y & 0xffff);
  base[3] = offs_s[3] + (int)(pre.y >> 16);
  base[4] = offs_s[4] + (int)(pre.z & 0xffff);
  base[5] = offs_s[5] + (int)(pre.z >> 16);
  base[6] = offs_s[6] + (int)(pre.w & 0xffff);
  base[7] = offs_s[7] + (int)(pre.w >> 16);
#pragma unroll
  for (int j = 0; j < 32; ++j) {
    int idx = tid * 32 + j;
    int e = eidx[j];
    int s = base[e]++;
    slot_token[s] = idx >> 1;
    slot_w[s] = tk_w[idx];
    slot_of[idx] = s;
  }
}

// ---------------------------------------------------------------------------
// GEMM: measured-best config (round-5/8): 256x256 tile, BK=64, 512 thr =
// 8 waves (2m x 4n), wave-tile 128x64. Single __syncthreads per K-step,
// double-buffered global_load_lds staging, XOR granule swizzle both sides
// (conflicts measured 0). ~120us per GEMM -- best across 8 structural
// variants.
// NEW (round-9): for STAGE==1, grid carries 3 extra z-slices (z=9..11,
// 384 blocks, dispatched last since z is the slowest index). These convert
// the FC2 weights f32->bf16 (sh_w2|e_w2 -> w2b|ew2b, 18M elems) while
// FC1's working blocks drain -- filling tail CUs and FC1's idle HBM BW
// (FC1 runs at 17% HBM). Removes ~35us of serialized conversion.
// STAGE 1: A=x_norm (z>0 gathered via slot_token), out = fast-GELU -> bf16.
// STAGE 2: A=hid (z>0 rows 4096+slot), out bf16 * (z==0 ? 1/9 : slot_w).
// ---------------------------------------------------------------------------
template <int N, int KD, int STAGE>
__global__ __launch_bounds__(512) void gemm2_k(
    const u16* __restrict__ Abase, const u16* __restrict__ Bsh,
    const u16* __restrict__ Bex, const float* __restrict__ bias_sh,
    const float* __restrict__ bias_ex,
    u16* __restrict__ outH,
    const int* __restrict__ offs, const int* __restrict__ slot_token,
    const float* __restrict__ slot_w,
    const float* __restrict__ csrc0, const float* __restrict__ csrc1,
    u16* __restrict__ cdst)
{
  constexpr int BK   = 64;
  constexpr int TILE = 256 * BK;        // u16 per A-or-B tile (16384)

  const int tid = threadIdx.x;
  const int z = blockIdx.z;

  if (STAGE == 1 && z >= 9) {
    // ---- FC2-weight conversion duty (guaranteed-dead z-slices) ----
    // 18,874,368 elems = 4608 chunks of 4096 (512 thr x 8). 384 cvt blocks.
    const int c0 = (z - 9) * 128 + blockIdx.y * 8 + blockIdx.x;
    for (int c = c0; c < 4608; c += 384) {
      const int64_t i0 = (int64_t)c * 4096 + (int64_t)tid * 8;
      const float* src; int64_t rel;
      if (i0 < 2097152) { src = csrc0; rel = i0; }
      else              { src = csrc1; rel = i0 - 2097152; }
      const float4 a = *(const float4*)(src + rel);
      const float4 b = *(const float4*)(src + rel + 4);
      union { u16 h[8]; uint4 v; } o;
      o.h[0] = f2bf(a.x); o.h[1] = f2bf(a.y); o.h[2] = f2bf(a.z); o.h[3] = f2bf(a.w);
      o.h[4] = f2bf(b.x); o.h[5] = f2bf(b.y); o.h[6] = f2bf(b.z); o.h[7] = f2bf(b.w);
      *(uint4*)(cdst + i0) = o.v;
    }
    return;
  }

  int off = 0, cnt = 4096, obase = 0;
  const u16* B = Bsh;
  const float* biasp = bias_sh;
  if (z > 0) {
    off = offs[z - 1]; cnt = offs[z] - off; obase = 4096 + off;
    B = Bex + (size_t)(z - 1) * N * KD;
    biasp = bias_ex + (size_t)(z - 1) * N;
  }
  const int m0 = blockIdx.y * 256;
  if (m0 >= cnt) return;
  const int n0 = blockIdx.x * 256;

  __shared__ u16 lds[4 * TILE];   // [buf][A|B][TILE] = 128 KiB

  const int w = tid >> 6, l = tid & 63;

  // ---- staging geometry (8 granules/row, 4 chunks of 64 rows each) ----
  const int rth = tid >> 3;            // row-within-chunk 0..63
  const int pgt = tid & 7;             // phys granule
  const int lg  = pgt ^ (rth & 7);     // logical granule (pre-swizzle)

  const u16* gA[4];
  const u16* gB[4];
#pragma unroll
  for (int j = 0; j < 4; ++j) {
    int r = m0 + j * 64 + rth;
    if (r > cnt - 1) r = cnt - 1;
    size_t arow;
    if (STAGE == 1) arow = (z == 0) ? (size_t)r : (size_t)slot_token[off + r];
    else            arow = (z == 0) ? (size_t)r : (size_t)(4096 + off + r);
    gA[j] = Abase + arow * KD + lg * 8;
    gB[j] = B + (size_t)(n0 + j * 64 + rth) * KD + lg * 8;
  }

  // ---- MFMA geometry (16x16x32; C/D: col=lane&15, row=(lane>>4)*4+reg) ----
  const int wm = w >> 2, wn = w & 3;    // wave tile: rows wm*128.., cols wn*64..
  const int fr = l & 15, fq = l >> 4;
  const int swzm = fr & 7;
  const int rowA = (wm * 128 + fr) * BK;   // u16, A frag row base (mi=0)
  const int rowB = (wn * 64 + fr) * BK;    // u16, B frag row base (ni=0)

  f32x4 acc[8][4];
  const f32x4 zero = {0.f, 0.f, 0.f, 0.f};
#pragma unroll
  for (int mi = 0; mi < 8; ++mi)
#pragma unroll
    for (int ni = 0; ni < 4; ++ni) acc[mi][ni] = zero;

  const int NT = KD / BK;

#define STAGE_TILE(d)                                                       \
  { u16* dst = lds + (d) * 2 * TILE;                                        \
    _Pragma("unroll") for (int j = 0; j < 4; ++j) {                         \
      ASYNC_COPY16(gA[j], dst + j * 4096 + w * 512); gA[j] += BK; }         \
    _Pragma("unroll") for (int j = 0; j < 4; ++j) {                         \
      ASYNC_COPY16(gB[j], dst + TILE + j * 4096 + w * 512); gB[j] += BK; } }

  // prologue: tile 0 -> buf 0
  STAGE_TILE(0);

  for (int kb = 0; kb < NT; ++kb) {
    const int cur = kb & 1;
    __syncthreads();            // drains prefetch of cur; reads of cur^1 done
    if (kb + 1 < NT) { STAGE_TILE(cur ^ 1); }

    const u16* sA = lds + cur * 2 * TILE;
    const u16* sB = sA + TILE;
#pragma unroll
    for (int ks = 0; ks < 2; ++ks) {
      const int sw = (((ks * 4 + fq) ^ swzm)) * 8;
      bf16x8 af[8], bv[4];
#pragma unroll
      for (int mi = 0; mi < 8; ++mi) af[mi] = *(const bf16x8*)(sA + rowA + mi * 16 * BK + sw);
#pragma unroll
      for (int ni = 0; ni < 4; ++ni) bv[ni] = *(const bf16x8*)(sB + rowB + ni * 16 * BK + sw);
#pragma unroll
      for (int mi = 0; mi < 8; ++mi)
#pragma unroll
        for (int ni = 0; ni < 4; ++ni)
          acc[mi][ni] = __builtin_amdgcn_mfma_f32_16x16x32_bf16(af[mi], bv[ni], acc[mi][ni], 0, 0, 0);
    }
  }

  // epilogue: C/D layout col=lane&15, row=(lane>>4)*4+reg
#pragma unroll
  for (int mi = 0; mi < 8; ++mi) {
    const int mlBase = m0 + wm * 128 + mi * 16 + fq * 4;
#pragma unroll
    for (int r = 0; r < 4; ++r) {
      const int ml = mlBase + r;
      if (ml >= cnt) continue;
      const size_t orow = (size_t)(obase + ml) * N;
      float rwgt = (STAGE == 2) ? ((z == 0) ? (1.0f / 9.0f) : slot_w[off + ml]) : 1.f;
#pragma unroll
      for (int ni = 0; ni < 4; ++ni) {
        const int col = n0 + wn * 64 + ni * 16 + fr;
        float v = acc[mi][ni][r] + biasp[col];
        if (STAGE == 1) v = gelu_fast(v);
        else            v = v * rwgt;
        outH[orow + col] = f2bf(v);
      }
    }
  }
#undef STAGE_TILE
}

// ---------------------------------------------------------------------------
// K5: combine shared + 2 expert slots (bf16), then LayerNorm over O.
// ---------------------------------------------------------------------------
__global__ __launch_bounds__(256) void combine_ln2_k(
    const u16* __restrict__ sh_out, const u16* __restrict__ eout,
    const int* __restrict__ slot_of,
    const float* __restrict__ g2, const float* __restrict__ b2,
    float* __restrict__ out)
{
  const int t = blockIdx.x, tid = threadIdx.x;
  const int wave = tid >> 6, lane = tid & 63;
  __shared__ float red[8];
  const size_t s0 = (size_t)slot_of[2 * t], s1 = (size_t)slot_of[2 * t + 1];
  union { uint2 v; u16 h[4]; } a, c0, c1;
  a.v  = *(const uint2*)(sh_out + (size_t)t * 1024 + 4 * tid);
  c0.v = *(const uint2*)(eout + s0 * 1024 + 4 * tid);
  c1.v = *(const uint2*)(eout + s1 * 1024 + 4 * tid);
  float vv[4];
#pragma unroll
  for (int j = 0; j < 4; ++j) vv[j] = bf2f(a.h[j]) + bf2f(c0.h[j]) + bf2f(c1.h[j]);
  float s = vv[0] + vv[1] + vv[2] + vv[3];
  float q = vv[0] * vv[0] + vv[1] * vv[1] + vv[2] * vv[2] + vv[3] * vv[3];
#pragma unroll
  for (int o = 32; o > 0; o >>= 1) { s += __shfl_down(s, o, 64); q += __shfl_down(q, o, 64); }
  if (lane == 0) { red[wave] = s; red[4 + wave] = q; }
  __syncthreads();
  if (tid == 0) {
    float S = red[0] + red[1] + red[2] + red[3];
    float Q = red[4] + red[5] + red[6] + red[7];
    float mean = S * (1.0f / 1024.0f);
    float var = Q * (1.0f / 1024.0f) - mean * mean;
    red[0] = mean; red[1] = rsqrtf(var + 1e-5f);
  }
  __syncthreads();
  const float mean = red[0], rstd = red[1];
#pragma unroll
  for (int j = 0; j < 4; ++j) {
    int d = 4 * tid + j;
    out[(size_t)t * 1024 + d] = (vv[j] - mean) * rstd * g2[d] + b2[d];
  }
}

// ---------------------------------------------------------------------------
extern "C" void kernel_launch(void* const* d_in, const int* in_sizes, int n_in,
                              void* d_out, int out_size, void* d_ws, size_t ws_size,
                              hipStream_t stream)
{
  const float* x     = (const float*)d_in[0];
  const float* ln1_g = (const float*)d_in[1];
  const float* ln1_b = (const float*)d_in[2];
  const float* rw    = (const float*)d_in[3];
  const float* rb    = (const float*)d_in[4];
  const float* sh_w1 = (const float*)d_in[5];
  const float* sh_b1 = (const float*)d_in[6];
  const float* sh_w2 = (const float*)d_in[7];
  const float* sh_b2 = (const float*)d_in[8];
  const float* e_w1  = (const float*)d_in[9];
  const float* e_b1  = (const float*)d_in[10];
  const float* e_w2  = (const float*)d_in[11];
  const float* e_b2  = (const float*)d_in[12];
  const float* ln2_g = (const float*)d_in[13];
  const float* ln2_b = (const float*)d_in[14];
  float* out = (float*)d_out;

  char* w = (char*)d_ws;
  u16*   x_norm = (u16*)(w + 0);              //  8 MiB  [4096,1024] bf16
  u16*   hid    = (u16*)(w + (8u << 20));     // 48 MiB  [12288,2048] bf16 (shared|slots)
  u16*   outb   = (u16*)(w + (56u << 20));    // 24 MiB  [12288,1024] bf16 (shared|slots)
  u16*   w1b    = (u16*)(w + (104u << 20));   //  4 MiB  [2048,1024]   (contig with ew1b)
  u16*   ew1b   = (u16*)(w + (108u << 20));   // 32 MiB  [8,2048,1024]
  u16*   w2b    = (u16*)(w + (140u << 20));   //  4 MiB  [1024,2048]   (contig with ew2b)
  u16*   ew2b   = (u16*)(w + (144u << 20));   // 32 MiB  [8,1024,2048]
  char*  meta   = w + (176u << 20);
  int*   tk_idx     = (int*)(meta);
  float* tk_w       = (float*)(meta + (32u << 10));
  int*   slot_token = (int*)(meta + (64u << 10));
  float* slot_w     = (float*)(meta + (96u << 10));
  int*   slot_of    = (int*)(meta + (128u << 10));
  int*   offs       = (int*)(meta + (160u << 10)); // 9 ints

  // FC1 weights f32 -> bf16 (w1b|ew1b contiguous, 18M elems)
  cvt1_k<<<9216, 256, 0, stream>>>(sh_w1, e_w1, w1b);

  ln_router_k<<<4096, 256, 0, stream>>>(x, ln1_g, ln1_b, rw, rb, x_norm, tk_idx, tk_w);
  assign_k<<<1, 256, 0, stream>>>(tk_idx, tk_w, offs, slot_token, slot_w, slot_of);

  // FC1 (z=0 shared + z=1..8 experts) -> fast GELU -> hid bf16.
  // z=9..11: 384 cvt blocks converting FC2 weights (sh_w2|e_w2 -> w2b|ew2b),
  // dispatched last -> they fill FC1's tail CUs / idle bandwidth.
  gemm2_k<2048, 1024, 1><<<dim3(8, 16, 12), 512, 0, stream>>>(
      x_norm, w1b, ew1b, sh_b1, e_b1, hid, offs, slot_token, nullptr,
      sh_w2, e_w2, w2b);
  // FC2 (z=0 shared + z=1..8 experts) -> scaled bf16 -> outb
  gemm2_k<1024, 2048, 2><<<dim3(4, 16, 9), 512, 0, stream>>>(
      hid, w2b, ew2b, sh_b2, e_b2, outb, offs, slot_token, slot_w,
      nullptr, nullptr, nullptr);

  combine_ln2_k<<<4096, 256, 0, stream>>>(outb, outb + (size_t)4096 * 1024,
                                          slot_of, ln2_g, ln2_b, out);
}